// Round 11
// baseline (661.449 us; speedup 1.0000x reference)
//
#include <hip/hip_runtime.h>
#include <hip/hip_bf16.h>

// RGAT encoder, round 11:
//  - GEMM: one block = 128 nodes x ALL 256 channels (x staged ONCE, half the
//    blocks, wave w == head w). Swapped-operand MFMA layout as r10.
//  - scatter writes ONLY czoff (4B/edge): kills the scattered-write
//    amplification (per-XCD 4MB L2 can't hold 18MB dirty working set).
//  - norm computes ee from elh/erh gathers (raw pass) then rescales in place:
//    all ceeh writes COALESCED (keys walked in order).
//  - aggregate: unchanged r9/r10 structure (merged segment, half-wave/edge).

#define RN 100000
#define RE 500000
#define RH 4
#define RIN 256
#define RR 3
#define RHF 256
#define NE3 (RR * RE)
#define N3  (RR * RN)

typedef __attribute__((ext_vector_type(8))) short short8;
typedef __attribute__((ext_vector_type(4))) float f32x4;

static __device__ __forceinline__ float b2f(unsigned short u) {
  return __uint_as_float(((unsigned int)u) << 16);
}
static __device__ __forceinline__ unsigned short f2b(float f) {
  unsigned int u = __float_as_uint(f);
  u += 0x7FFF + ((u >> 16) & 1);   // RNE
  return (unsigned short)(u >> 16);
}
static __device__ __forceinline__ float h2f(unsigned short u) {
  return (float)__builtin_bit_cast(_Float16, u);
}
static __device__ __forceinline__ unsigned short f2h(float f) {
  return __builtin_bit_cast(unsigned short, (_Float16)f);
}
static __device__ __forceinline__ unsigned int cvt_pk_bf16(float lo, float hi) {
  unsigned int r;
  asm("v_cvt_pk_bf16_f32 %0, %1, %2" : "=v"(r) : "v"(lo), "v"(hi));
  return r;
}

// ---------------- conversions ----------------
__global__ __launch_bounds__(256) void rgat_convx(
    const float* __restrict__ x, unsigned short* __restrict__ xb) {
  const size_t i = ((size_t)blockIdx.x * 256 + threadIdx.x) * 4;
  if (i >= (size_t)RN * RIN) return;
  const float4 v = *(const float4*)(x + i);
  ushort4 o;
  o.x = f2b(v.x); o.y = f2b(v.y); o.z = f2b(v.z); o.w = f2b(v.w);
  *(ushort4*)(xb + i) = o;
}

// W[r][k][n] f32 -> Wbt[r][n][k] bf16
__global__ __launch_bounds__(256) void rgat_convw(
    const float* __restrict__ W, unsigned short* __restrict__ wbt) {
  const int o = blockIdx.x * 256 + threadIdx.x;
  if (o >= RR * RIN * RHF) return;
  const int r = o / (RIN * RHF);
  const int rem = o - r * (RIN * RHF);
  const int n = rem >> 8;
  const int k = rem & 255;
  wbt[o] = f2b(W[r * (RIN * RHF) + k * RHF + n]);
}

// ---- GEMM: block = 128 nodes x 256 channels; C[ch,node]; packed z-store ----
__global__ __launch_bounds__(256) void rgat_gemm_bf16(
    const unsigned short* __restrict__ xb, const unsigned short* __restrict__ wbt,
    unsigned short* __restrict__ zb, const float* __restrict__ al,
    const float* __restrict__ ar, unsigned short* __restrict__ elh,
    unsigned short* __restrict__ erh) {
  __shared__ unsigned short As[128 * 32];   // x node rows      (8 KB)
  __shared__ unsigned short Bs[256 * 32];   // W channel rows   (16 KB)
  const int tid = threadIdx.x;
  const int lane = tid & 63, wid = tid >> 6;
  const int m0 = blockIdx.x * 128;          // node tile
  const int r  = blockIdx.y;

  f32x4 acc[4][8] = {};   // [ci][xi]
  const unsigned short* Bbase = wbt + (size_t)r * (RIN * RHF);

  for (int k0 = 0; k0 < RIN; k0 += 32) {
    // As: 512 x 16B chunks, 2 per thread
#pragma unroll
    for (int i = 0; i < 2; ++i) {
      const int c = i * 256 + tid;
      const int row = c >> 2, c4 = c & 3;
      const unsigned short* ga = xb + (size_t)(m0 + row) * RIN + k0 + c4 * 8;
      __builtin_amdgcn_global_load_lds(
          (const __attribute__((address_space(1))) void*)ga,
          (__attribute__((address_space(3))) void*)(As + c * 8), 16, 0, 0);
    }
    // Bs: 1024 x 16B chunks, 4 per thread
#pragma unroll
    for (int i = 0; i < 4; ++i) {
      const int c = i * 256 + tid;
      const int row = c >> 2, c4 = c & 3;
      const unsigned short* gb = Bbase + (size_t)row * RIN + k0 + c4 * 8;
      __builtin_amdgcn_global_load_lds(
          (const __attribute__((address_space(1))) void*)gb,
          (__attribute__((address_space(3))) void*)(Bs + c * 8), 16, 0, 0);
    }
    asm volatile("s_waitcnt vmcnt(0)" ::: "memory");
    __syncthreads();

    short8 wf[4], xf[8];
#pragma unroll
    for (int ci = 0; ci < 4; ++ci)
      wf[ci] = *(const short8*)(Bs + ((wid * 64 + ci * 16 + (lane & 15)) * 32 + (lane >> 4) * 8));
#pragma unroll
    for (int xi = 0; xi < 8; ++xi)
      xf[xi] = *(const short8*)(As + ((xi * 16 + (lane & 15)) * 32 + (lane >> 4) * 8));
#pragma unroll
    for (int ci = 0; ci < 4; ++ci)
#pragma unroll
      for (int xi = 0; xi < 8; ++xi)
        acc[ci][xi] = __builtin_amdgcn_mfma_f32_16x16x32_bf16(wf[ci], xf[xi], acc[ci][xi], 0, 0, 0);
    __syncthreads();
  }

  // epilogue: wave wid owns channels wid*64..wid*64+63 == head wid.
  const int head = wid;
  const int g4 = (lane >> 4) * 4;
  float alv[4][4], arv[4][4];
#pragma unroll
  for (int ci = 0; ci < 4; ++ci) {
    const float4 a4 = *(const float4*)(al + r * RHF + head * 64 + ci * 16 + g4);
    const float4 b4 = *(const float4*)(ar + r * RHF + head * 64 + ci * 16 + g4);
    alv[ci][0] = a4.x; alv[ci][1] = a4.y; alv[ci][2] = a4.z; alv[ci][3] = a4.w;
    arv[ci][0] = b4.x; arv[ci][1] = b4.y; arv[ci][2] = b4.z; arv[ci][3] = b4.w;
  }

#pragma unroll
  for (int xi = 0; xi < 8; ++xi) {
    const int node = m0 + xi * 16 + (lane & 15);
    unsigned short* zrow = zb + (size_t)r * ((size_t)RN * RHF) + (size_t)node * RHF
                           + head * 64 + g4;
    float pl = 0.f, pr = 0.f;
#pragma unroll
    for (int ci = 0; ci < 4; ++ci) {
      const f32x4 a = acc[ci][xi];
      uint2 pk;
      pk.x = cvt_pk_bf16(a[0], a[1]);
      pk.y = cvt_pk_bf16(a[2], a[3]);
      if (node < RN) *(uint2*)(zrow + ci * 16) = pk;
      pl += a[0] * alv[ci][0] + a[1] * alv[ci][1] + a[2] * alv[ci][2] + a[3] * alv[ci][3];
      pr += a[0] * arv[ci][0] + a[1] * arv[ci][1] + a[2] * arv[ci][2] + a[3] * arv[ci][3];
    }
    pl += __shfl_xor(pl, 16); pl += __shfl_xor(pl, 32);
    pr += __shfl_xor(pr, 16); pr += __shfl_xor(pr, 32);
    if (lane < 16 && node < RN) {
      const size_t key = (size_t)r * RN + node;
      elh[key * RH + head] = f2h(pl);
      erh[key * RH + head] = f2h(pr);
    }
  }
}

// ---------------- CSR build keyed by (node, relation) ----------------
__global__ __launch_bounds__(256) void rgat_hist(
    const int* __restrict__ dst, int* __restrict__ deg2) {
  const int i = blockIdx.x * 256 + threadIdx.x;
  if (i >= NE3) return;
  const int r = i / RE;
  atomicAdd(&deg2[dst[i] * RR + r], 1);
}

__global__ __launch_bounds__(256) void rgat_scan1(
    const int* __restrict__ deg, int* __restrict__ offs, int* __restrict__ bsum) {
  __shared__ int sh[256];
  const int tid = threadIdx.x;
  const int base = blockIdx.x * 1024 + tid * 4;
  int v[4]; int s = 0;
#pragma unroll
  for (int j = 0; j < 4; ++j) {
    v[j] = (base + j < N3) ? deg[base + j] : 0;
    s += v[j];
  }
  sh[tid] = s;
  __syncthreads();
  for (int off = 1; off < 256; off <<= 1) {
    int t = (tid >= off) ? sh[tid - off] : 0;
    __syncthreads();
    sh[tid] += t;
    __syncthreads();
  }
  int run = sh[tid] - s;
  if (tid == 255) bsum[blockIdx.x] = sh[255];
#pragma unroll
  for (int j = 0; j < 4; ++j) {
    if (base + j < N3) offs[base + j] = run;
    run += v[j];
  }
}

__global__ __launch_bounds__(512) void rgat_scan2(int* __restrict__ bsum, int nb) {
  __shared__ int sh[512];
  const int tid = threadIdx.x;
  const int v = (tid < nb) ? bsum[tid] : 0;
  sh[tid] = v;
  __syncthreads();
  for (int off = 1; off < 512; off <<= 1) {
    int t = (tid >= off) ? sh[tid - off] : 0;
    __syncthreads();
    sh[tid] += t;
    __syncthreads();
  }
  if (tid < nb) bsum[tid] = sh[tid] - v;
}

__global__ __launch_bounds__(256) void rgat_scan3(
    int* __restrict__ offs, const int* __restrict__ bsum) {
  const int base = blockIdx.x * 1024 + threadIdx.x * 4;
  const int b = bsum[blockIdx.x];
#pragma unroll
  for (int j = 0; j < 4; ++j)
    if (base + j < N3) offs[base + j] += b;
}

// scatter: czoff[pos] = r*RN+src ONLY (no edge-data writes)
__global__ __launch_bounds__(256) void rgat_scatter(
    const int* __restrict__ src, const int* __restrict__ dst,
    int* __restrict__ offs2, int* __restrict__ czoff) {
  const int i = blockIdx.x * 256 + threadIdx.x;
  if (i >= NE3) return;
  const int r = i / RE;
  const int s = src[i];
  const int d = dst[i];
  const int pos = atomicAdd(&offs2[d * RR + r], 1);
  czoff[pos] = r * RN + s;
}

// norm: one thread per key; pass1 compute raw ee (gather elh) + sum;
// pass2 rescale in place. All ceeh writes coalesced (keys in order).
__global__ __launch_bounds__(256) void rgat_norm(
    const int* __restrict__ czoff, const unsigned short* __restrict__ elh,
    const unsigned short* __restrict__ erh, const int* __restrict__ deg2,
    const int* __restrict__ offs2, unsigned short* __restrict__ ceeh) {
  const int key = blockIdx.x * 256 + threadIdx.x;
  if (key >= N3) return;
  const int d = deg2[key];
  if (d == 0) return;
  const int end = offs2[key];        // segment END after scatter
  const int r = key % RR;
  const int dnode = key / RR;
  const uint2 ru = *(const uint2*)(erh + ((size_t)r * RN + dnode) * RH);
  const float er0 = h2f((unsigned short)ru.x), er1 = h2f((unsigned short)(ru.x >> 16));
  const float er2 = h2f((unsigned short)ru.y), er3 = h2f((unsigned short)(ru.y >> 16));
  float s0 = 0.f, s1 = 0.f, s2 = 0.f, s3 = 0.f;
  for (int p = end - d; p < end; ++p) {
    const int zo = czoff[p];
    const uint2 eu = *(const uint2*)(elh + (size_t)zo * RH);
    float e0 = h2f((unsigned short)eu.x) + er0;
    float e1 = h2f((unsigned short)(eu.x >> 16)) + er1;
    float e2 = h2f((unsigned short)eu.y) + er2;
    float e3 = h2f((unsigned short)(eu.y >> 16)) + er3;
    e0 = e0 > 0.f ? e0 : 0.2f * e0;
    e1 = e1 > 0.f ? e1 : 0.2f * e1;
    e2 = e2 > 0.f ? e2 : 0.2f * e2;
    e3 = e3 > 0.f ? e3 : 0.2f * e3;
    const float p0 = __expf(e0), p1 = __expf(e1), p2 = __expf(e2), p3 = __expf(e3);
    s0 += p0; s1 += p1; s2 += p2; s3 += p3;
    uint2 o;
    o.x = (unsigned int)f2h(p0) | ((unsigned int)f2h(p1) << 16);
    o.y = (unsigned int)f2h(p2) | ((unsigned int)f2h(p3) << 16);
    *(uint2*)(ceeh + (size_t)p * 4) = o;
  }
  const float i0 = s0 > 0.f ? 1.f / s0 : 0.f;
  const float i1 = s1 > 0.f ? 1.f / s1 : 0.f;
  const float i2 = s2 > 0.f ? 1.f / s2 : 0.f;
  const float i3 = s3 > 0.f ? 1.f / s3 : 0.f;
  for (int p = end - d; p < end; ++p) {
    uint2 v = *(const uint2*)(ceeh + (size_t)p * 4);
    const float a0 = h2f((unsigned short)v.x) * i0;
    const float a1 = h2f((unsigned short)(v.x >> 16)) * i1;
    const float a2 = h2f((unsigned short)v.y) * i2;
    const float a3 = h2f((unsigned short)(v.y >> 16)) * i3;
    v.x = (unsigned int)f2h(a0) | ((unsigned int)f2h(a1) << 16);
    v.y = (unsigned int)f2h(a2) | ((unsigned int)f2h(a3) << 16);
    *(uint2*)(ceeh + (size_t)p * 4) = v;
  }
}

// -------- aggregate: block per node; half-wave per edge over MERGED segment --
__global__ __launch_bounds__(256) void rgat_aggregate(
    const unsigned short* __restrict__ zb, const int* __restrict__ czoff,
    const unsigned short* __restrict__ ceeh, const int* __restrict__ deg2,
    const int* __restrict__ offs2, const float* __restrict__ bias,
    float* __restrict__ out) {
  __shared__ float shn[4][RHF];   // 4 KB
  const int n = blockIdx.x;
  const int tid = threadIdx.x;
  const int wid = tid >> 6, lane = tid & 63;
  const int hw = lane >> 5;
  const int sub = lane & 31;
  const int hwid = wid * 2 + hw;      // half-wave id 0..7
  const int h = sub >> 3;             // head of my 8 columns
  const int c = sub * 8;              // my 8 columns

  const int k0 = n * RR;
  const int start = offs2[k0] - deg2[k0];
  const int dm = offs2[k0 + 2] - start;

  float acc[8] = {};
  const unsigned short* zB = zb + c;

  for (int base = 0; base < dm; base += 16) {
    int ss[2]; float aa[2];
#pragma unroll
    for (int j = 0; j < 2; ++j) {
      const int t = base + j * 8 + hwid;
      const int tc = t < dm ? t : dm - 1;
      const int p = start + tc;
      ss[j] = czoff[p];
      const float af = h2f(ceeh[(size_t)p * 4 + h]);
      aa[j] = t < dm ? af : 0.f;
    }
    short8 zv[2];
#pragma unroll
    for (int j = 0; j < 2; ++j)
      zv[j] = *(const short8*)(zB + (size_t)ss[j] * RHF);
#pragma unroll
    for (int j = 0; j < 2; ++j) {
      const float a = aa[j];
#pragma unroll
      for (int k = 0; k < 8; ++k)
        acc[k] += a * b2f((unsigned short)zv[j][k]);
    }
  }

#pragma unroll
  for (int k = 0; k < 8; ++k) acc[k] += __shfl_xor(acc[k], 32);

  if (lane < 32) {
    *(float4*)&shn[wid][c]     = make_float4(acc[0], acc[1], acc[2], acc[3]);
    *(float4*)&shn[wid][c + 4] = make_float4(acc[4], acc[5], acc[6], acc[7]);
  }
  __syncthreads();

  const int col = tid;
  float v = shn[0][col] + shn[1][col] + shn[2][col] + shn[3][col]
          + bias[col] + bias[RHF + col] + bias[2 * RHF + col];
  v = v > 0.f ? v : (__expf(v) - 1.f);
  out[(size_t)n * RHF + col] = v;
}

extern "C" void kernel_launch(void* const* d_in, const int* in_sizes, int n_in,
                              void* d_out, int out_size, void* d_ws, size_t ws_size,
                              hipStream_t stream) {
  const float* x    = (const float*)d_in[0];
  const float* W    = (const float*)d_in[1];
  const float* al   = (const float*)d_in[2];
  const float* ar   = (const float*)d_in[3];
  const float* bias = (const float*)d_in[4];
  const int*   src  = (const int*)d_in[5];
  const int*   dst  = (const int*)d_in[6];
  float* out = (float*)d_out;

  // workspace layout (bytes), total ~232 MB
  char* p = (char*)d_ws;
  unsigned short* xb   = (unsigned short*)p; p += (size_t)RN * RIN * 2;        // 51.2 MB
  unsigned short* wbt  = (unsigned short*)p; p += (size_t)RR * RIN * RHF * 2;  // 0.39 MB
  unsigned short* zb   = (unsigned short*)p; p += (size_t)RR * RN * RHF * 2;   // 153.6 MB
  unsigned short* elh  = (unsigned short*)p; p += (size_t)N3 * RH * 2;         // 2.4 MB
  unsigned short* erh  = (unsigned short*)p; p += (size_t)N3 * RH * 2;         // 2.4 MB
  int* deg2    = (int*)p;    p += (size_t)N3 * 4;                              // 1.2 MB
  int* offs2   = (int*)p;    p += (size_t)N3 * 4;                              // 1.2 MB
  int* czoff   = (int*)p;    p += (size_t)NE3 * 4;                             // 6.0 MB
  unsigned short* ceeh = (unsigned short*)p; p += (size_t)NE3 * RH * 2;        // 12.0 MB
  int* bsum    = (int*)p;    p += 2048;

  const int NB1 = (N3 + 1023) / 1024;   // 293

  hipMemsetAsync(deg2, 0, (size_t)N3 * 4, stream);

  rgat_convx<<<(RN * RIN / 4 + 255) / 256, 256, 0, stream>>>(x, xb);
  rgat_convw<<<(RR * RIN * RHF + 255) / 256, 256, 0, stream>>>(W, wbt);

  rgat_hist<<<(NE3 + 255) / 256, 256, 0, stream>>>(dst, deg2);
  rgat_scan1<<<NB1, 256, 0, stream>>>(deg2, offs2, bsum);
  rgat_scan2<<<1, 512, 0, stream>>>(bsum, NB1);
  rgat_scan3<<<NB1, 256, 0, stream>>>(offs2, bsum);

  rgat_gemm_bf16<<<dim3((RN + 127) / 128, RR), 256, 0, stream>>>(
      xb, wbt, zb, al, ar, elh, erh);

  rgat_scatter<<<(NE3 + 255) / 256, 256, 0, stream>>>(src, dst, offs2, czoff);

  rgat_norm<<<(N3 + 255) / 256, 256, 0, stream>>>(czoff, elh, erh, deg2, offs2, ceeh);

  rgat_aggregate<<<RN, 256, 0, stream>>>(zb, czoff, ceeh, deg2, offs2, bias, out);
}

// Round 13
// 618.527 us; speedup vs baseline: 1.0694x; 1.0694x over previous
//
#include <hip/hip_runtime.h>
#include <hip/hip_bf16.h>

// RGAT encoder, round 12 (resubmit — r12 bench hit GPUAcquisitionTimeout):
//  - r10 scatter/norm split RESTORED (r11 lesson: edge-parallel scattered
//    gathers beat key-serial "coalesced" ones — norm's elh gathers were the
//    661us regression). scatter: czoff + raw f16 ee (edge-parallel exp).
//    norm: 2 coalesced in-place passes per key.
//  - r11 GEMM kept: block = 128 nodes x all 256 channels, x staged once/rel.
//  - convx + convw + hist merged into ONE rgat_prep kernel (independent tasks,
//    BW-bound + atomic-latency-bound co-scheduled).
//  - aggregate unchanged (merged segment, half-wave/edge, stride-1).

#define RN 100000
#define RE 500000
#define RH 4
#define RIN 256
#define RR 3
#define RHF 256
#define NE3 (RR * RE)
#define N3  (RR * RN)

#define CVX_BLOCKS ((RN * RIN / 4 + 255) / 256)         // 25000
#define CVW_BLOCKS ((RR * RIN * RHF + 255) / 256)       // 768
#define HIST_BLOCKS ((NE3 + 255) / 256)                 // 5860

typedef __attribute__((ext_vector_type(8))) short short8;
typedef __attribute__((ext_vector_type(4))) float f32x4;

static __device__ __forceinline__ float b2f(unsigned short u) {
  return __uint_as_float(((unsigned int)u) << 16);
}
static __device__ __forceinline__ unsigned short f2b(float f) {
  unsigned int u = __float_as_uint(f);
  u += 0x7FFF + ((u >> 16) & 1);   // RNE
  return (unsigned short)(u >> 16);
}
static __device__ __forceinline__ float h2f(unsigned short u) {
  return (float)__builtin_bit_cast(_Float16, u);
}
static __device__ __forceinline__ unsigned short f2h(float f) {
  return __builtin_bit_cast(unsigned short, (_Float16)f);
}
static __device__ __forceinline__ unsigned int cvt_pk_bf16(float lo, float hi) {
  unsigned int r;
  asm("v_cvt_pk_bf16_f32 %0, %1, %2" : "=v"(r) : "v"(lo), "v"(hi));
  return r;
}

// ---- prep: convx | convw | hist fused (independent tasks, range-split grid)
__global__ __launch_bounds__(256) void rgat_prep(
    const float* __restrict__ x, unsigned short* __restrict__ xb,
    const float* __restrict__ W, unsigned short* __restrict__ wbt,
    const int* __restrict__ dst, int* __restrict__ deg2) {
  const int b = blockIdx.x;
  if (b < CVX_BLOCKS) {
    const size_t i = ((size_t)b * 256 + threadIdx.x) * 4;
    if (i >= (size_t)RN * RIN) return;
    const float4 v = *(const float4*)(x + i);
    ushort4 o;
    o.x = f2b(v.x); o.y = f2b(v.y); o.z = f2b(v.z); o.w = f2b(v.w);
    *(ushort4*)(xb + i) = o;
  } else if (b < CVX_BLOCKS + CVW_BLOCKS) {
    const int o = (b - CVX_BLOCKS) * 256 + threadIdx.x;
    if (o >= RR * RIN * RHF) return;
    const int r = o / (RIN * RHF);
    const int rem = o - r * (RIN * RHF);
    const int n = rem >> 8;
    const int k = rem & 255;
    wbt[o] = f2b(W[r * (RIN * RHF) + k * RHF + n]);
  } else {
    const int i = (b - CVX_BLOCKS - CVW_BLOCKS) * 256 + threadIdx.x;
    if (i >= NE3) return;
    const int r = i / RE;
    atomicAdd(&deg2[dst[i] * RR + r], 1);
  }
}

// ---- GEMM: block = 128 nodes x 256 channels; C[ch,node]; packed z-store ----
__global__ __launch_bounds__(256) void rgat_gemm_bf16(
    const unsigned short* __restrict__ xb, const unsigned short* __restrict__ wbt,
    unsigned short* __restrict__ zb, const float* __restrict__ al,
    const float* __restrict__ ar, unsigned short* __restrict__ elh,
    unsigned short* __restrict__ erh) {
  __shared__ unsigned short As[128 * 32];   // x node rows      (8 KB)
  __shared__ unsigned short Bs[256 * 32];   // W channel rows   (16 KB)
  const int tid = threadIdx.x;
  const int lane = tid & 63, wid = tid >> 6;
  const int m0 = blockIdx.x * 128;          // node tile
  const int r  = blockIdx.y;

  f32x4 acc[4][8] = {};   // [ci][xi]
  const unsigned short* Bbase = wbt + (size_t)r * (RIN * RHF);

  for (int k0 = 0; k0 < RIN; k0 += 32) {
#pragma unroll
    for (int i = 0; i < 2; ++i) {
      const int c = i * 256 + tid;
      const int row = c >> 2, c4 = c & 3;
      const unsigned short* ga = xb + (size_t)(m0 + row) * RIN + k0 + c4 * 8;
      __builtin_amdgcn_global_load_lds(
          (const __attribute__((address_space(1))) void*)ga,
          (__attribute__((address_space(3))) void*)(As + c * 8), 16, 0, 0);
    }
#pragma unroll
    for (int i = 0; i < 4; ++i) {
      const int c = i * 256 + tid;
      const int row = c >> 2, c4 = c & 3;
      const unsigned short* gb = Bbase + (size_t)row * RIN + k0 + c4 * 8;
      __builtin_amdgcn_global_load_lds(
          (const __attribute__((address_space(1))) void*)gb,
          (__attribute__((address_space(3))) void*)(Bs + c * 8), 16, 0, 0);
    }
    asm volatile("s_waitcnt vmcnt(0)" ::: "memory");
    __syncthreads();

    short8 wf[4], xf[8];
#pragma unroll
    for (int ci = 0; ci < 4; ++ci)
      wf[ci] = *(const short8*)(Bs + ((wid * 64 + ci * 16 + (lane & 15)) * 32 + (lane >> 4) * 8));
#pragma unroll
    for (int xi = 0; xi < 8; ++xi)
      xf[xi] = *(const short8*)(As + ((xi * 16 + (lane & 15)) * 32 + (lane >> 4) * 8));
#pragma unroll
    for (int ci = 0; ci < 4; ++ci)
#pragma unroll
      for (int xi = 0; xi < 8; ++xi)
        acc[ci][xi] = __builtin_amdgcn_mfma_f32_16x16x32_bf16(wf[ci], xf[xi], acc[ci][xi], 0, 0, 0);
    __syncthreads();
  }

  const int head = wid;
  const int g4 = (lane >> 4) * 4;
  float alv[4][4], arv[4][4];
#pragma unroll
  for (int ci = 0; ci < 4; ++ci) {
    const float4 a4 = *(const float4*)(al + r * RHF + head * 64 + ci * 16 + g4);
    const float4 b4 = *(const float4*)(ar + r * RHF + head * 64 + ci * 16 + g4);
    alv[ci][0] = a4.x; alv[ci][1] = a4.y; alv[ci][2] = a4.z; alv[ci][3] = a4.w;
    arv[ci][0] = b4.x; arv[ci][1] = b4.y; arv[ci][2] = b4.z; arv[ci][3] = b4.w;
  }

#pragma unroll
  for (int xi = 0; xi < 8; ++xi) {
    const int node = m0 + xi * 16 + (lane & 15);
    unsigned short* zrow = zb + (size_t)r * ((size_t)RN * RHF) + (size_t)node * RHF
                           + head * 64 + g4;
    float pl = 0.f, pr = 0.f;
#pragma unroll
    for (int ci = 0; ci < 4; ++ci) {
      const f32x4 a = acc[ci][xi];
      uint2 pk;
      pk.x = cvt_pk_bf16(a[0], a[1]);
      pk.y = cvt_pk_bf16(a[2], a[3]);
      if (node < RN) *(uint2*)(zrow + ci * 16) = pk;
      pl += a[0] * alv[ci][0] + a[1] * alv[ci][1] + a[2] * alv[ci][2] + a[3] * alv[ci][3];
      pr += a[0] * arv[ci][0] + a[1] * arv[ci][1] + a[2] * arv[ci][2] + a[3] * arv[ci][3];
    }
    pl += __shfl_xor(pl, 16); pl += __shfl_xor(pl, 32);
    pr += __shfl_xor(pr, 16); pr += __shfl_xor(pr, 32);
    if (lane < 16 && node < RN) {
      const size_t key = (size_t)r * RN + node;
      elh[key * RH + head] = f2h(pl);
      erh[key * RH + head] = f2h(pr);
    }
  }
}

// ---------------- scans ----------------
__global__ __launch_bounds__(256) void rgat_scan1(
    const int* __restrict__ deg, int* __restrict__ offs, int* __restrict__ bsum) {
  __shared__ int sh[256];
  const int tid = threadIdx.x;
  const int base = blockIdx.x * 1024 + tid * 4;
  int v[4]; int s = 0;
#pragma unroll
  for (int j = 0; j < 4; ++j) {
    v[j] = (base + j < N3) ? deg[base + j] : 0;
    s += v[j];
  }
  sh[tid] = s;
  __syncthreads();
  for (int off = 1; off < 256; off <<= 1) {
    int t = (tid >= off) ? sh[tid - off] : 0;
    __syncthreads();
    sh[tid] += t;
    __syncthreads();
  }
  int run = sh[tid] - s;
  if (tid == 255) bsum[blockIdx.x] = sh[255];
#pragma unroll
  for (int j = 0; j < 4; ++j) {
    if (base + j < N3) offs[base + j] = run;
    run += v[j];
  }
}

__global__ __launch_bounds__(512) void rgat_scan2(int* __restrict__ bsum, int nb) {
  __shared__ int sh[512];
  const int tid = threadIdx.x;
  const int v = (tid < nb) ? bsum[tid] : 0;
  sh[tid] = v;
  __syncthreads();
  for (int off = 1; off < 512; off <<= 1) {
    int t = (tid >= off) ? sh[tid - off] : 0;
    __syncthreads();
    sh[tid] += t;
    __syncthreads();
  }
  if (tid < nb) bsum[tid] = sh[tid] - v;
}

__global__ __launch_bounds__(256) void rgat_scan3(
    int* __restrict__ offs, const int* __restrict__ bsum) {
  const int base = blockIdx.x * 1024 + threadIdx.x * 4;
  const int b = bsum[blockIdx.x];
#pragma unroll
  for (int j = 0; j < 4; ++j)
    if (base + j < N3) offs[base + j] += b;
}

// scatter: czoff[pos] = r*RN+src, ceeh[pos] = f16x4 raw exp numerators
__global__ __launch_bounds__(256) void rgat_scatter(
    const int* __restrict__ src, const int* __restrict__ dst,
    const unsigned short* __restrict__ elh, const unsigned short* __restrict__ erh,
    int* __restrict__ offs2, int* __restrict__ czoff,
    unsigned short* __restrict__ ceeh) {
  const int i = blockIdx.x * 256 + threadIdx.x;
  if (i >= NE3) return;
  const int r = i / RE;
  const int s = src[i];
  const int d = dst[i];
  const int pos = atomicAdd(&offs2[d * RR + r], 1);
  const uint2 eu = *(const uint2*)(elh + ((size_t)r * RN + s) * RH);
  const uint2 ru = *(const uint2*)(erh + ((size_t)r * RN + d) * RH);
  float e0 = h2f((unsigned short)eu.x) + h2f((unsigned short)ru.x);
  float e1 = h2f((unsigned short)(eu.x >> 16)) + h2f((unsigned short)(ru.x >> 16));
  float e2 = h2f((unsigned short)eu.y) + h2f((unsigned short)ru.y);
  float e3 = h2f((unsigned short)(eu.y >> 16)) + h2f((unsigned short)(ru.y >> 16));
  e0 = e0 > 0.f ? e0 : 0.2f * e0;
  e1 = e1 > 0.f ? e1 : 0.2f * e1;
  e2 = e2 > 0.f ? e2 : 0.2f * e2;
  e3 = e3 > 0.f ? e3 : 0.2f * e3;
  czoff[pos] = r * RN + s;
  uint2 o;
  o.x = (unsigned int)f2h(__expf(e0)) | ((unsigned int)f2h(__expf(e1)) << 16);
  o.y = (unsigned int)f2h(__expf(e2)) | ((unsigned int)f2h(__expf(e3)) << 16);
  *(uint2*)(ceeh + (size_t)pos * 4) = o;
}

// norm: one thread per key; sum contiguous segment, rescale in place (coalesced)
__global__ __launch_bounds__(256) void rgat_norm(
    unsigned short* __restrict__ ceeh, const int* __restrict__ deg2,
    const int* __restrict__ offs2) {
  const int key = blockIdx.x * 256 + threadIdx.x;
  if (key >= N3) return;
  const int d = deg2[key];
  const int end = offs2[key];
  float s0 = 0.f, s1 = 0.f, s2 = 0.f, s3 = 0.f;
  for (int p = end - d; p < end; ++p) {
    const uint2 v = *(const uint2*)(ceeh + (size_t)p * 4);
    s0 += h2f((unsigned short)v.x);
    s1 += h2f((unsigned short)(v.x >> 16));
    s2 += h2f((unsigned short)v.y);
    s3 += h2f((unsigned short)(v.y >> 16));
  }
  const float i0 = s0 > 0.f ? 1.f / s0 : 0.f;
  const float i1 = s1 > 0.f ? 1.f / s1 : 0.f;
  const float i2 = s2 > 0.f ? 1.f / s2 : 0.f;
  const float i3 = s3 > 0.f ? 1.f / s3 : 0.f;
  for (int p = end - d; p < end; ++p) {
    uint2 v = *(const uint2*)(ceeh + (size_t)p * 4);
    const float a0 = h2f((unsigned short)v.x) * i0;
    const float a1 = h2f((unsigned short)(v.x >> 16)) * i1;
    const float a2 = h2f((unsigned short)v.y) * i2;
    const float a3 = h2f((unsigned short)(v.y >> 16)) * i3;
    v.x = (unsigned int)f2h(a0) | ((unsigned int)f2h(a1) << 16);
    v.y = (unsigned int)f2h(a2) | ((unsigned int)f2h(a3) << 16);
    *(uint2*)(ceeh + (size_t)p * 4) = v;
  }
}

// -------- aggregate: block per node; half-wave per edge over MERGED segment --
__global__ __launch_bounds__(256) void rgat_aggregate(
    const unsigned short* __restrict__ zb, const int* __restrict__ czoff,
    const unsigned short* __restrict__ ceeh, const int* __restrict__ deg2,
    const int* __restrict__ offs2, const float* __restrict__ bias,
    float* __restrict__ out) {
  __shared__ float shn[4][RHF];   // 4 KB
  const int n = blockIdx.x;
  const int tid = threadIdx.x;
  const int wid = tid >> 6, lane = tid & 63;
  const int hw = lane >> 5;
  const int sub = lane & 31;
  const int hwid = wid * 2 + hw;      // half-wave id 0..7
  const int h = sub >> 3;             // head of my 8 columns
  const int c = sub * 8;              // my 8 columns

  const int k0 = n * RR;
  const int start = offs2[k0] - deg2[k0];
  const int dm = offs2[k0 + 2] - start;

  float acc[8] = {};
  const unsigned short* zB = zb + c;

  for (int base = 0; base < dm; base += 16) {
    int ss[2]; float aa[2];
#pragma unroll
    for (int j = 0; j < 2; ++j) {
      const int t = base + j * 8 + hwid;
      const int tc = t < dm ? t : dm - 1;
      const int p = start + tc;
      ss[j] = czoff[p];
      const float af = h2f(ceeh[(size_t)p * 4 + h]);
      aa[j] = t < dm ? af : 0.f;
    }
    short8 zv[2];
#pragma unroll
    for (int j = 0; j < 2; ++j)
      zv[j] = *(const short8*)(zB + (size_t)ss[j] * RHF);
#pragma unroll
    for (int j = 0; j < 2; ++j) {
      const float a = aa[j];
#pragma unroll
      for (int k = 0; k < 8; ++k)
        acc[k] += a * b2f((unsigned short)zv[j][k]);
    }
  }

#pragma unroll
  for (int k = 0; k < 8; ++k) acc[k] += __shfl_xor(acc[k], 32);

  if (lane < 32) {
    *(float4*)&shn[wid][c]     = make_float4(acc[0], acc[1], acc[2], acc[3]);
    *(float4*)&shn[wid][c + 4] = make_float4(acc[4], acc[5], acc[6], acc[7]);
  }
  __syncthreads();

  const int col = tid;
  float v = shn[0][col] + shn[1][col] + shn[2][col] + shn[3][col]
          + bias[col] + bias[RHF + col] + bias[2 * RHF + col];
  v = v > 0.f ? v : (__expf(v) - 1.f);
  out[(size_t)n * RHF + col] = v;
}

extern "C" void kernel_launch(void* const* d_in, const int* in_sizes, int n_in,
                              void* d_out, int out_size, void* d_ws, size_t ws_size,
                              hipStream_t stream) {
  const float* x    = (const float*)d_in[0];
  const float* W    = (const float*)d_in[1];
  const float* al   = (const float*)d_in[2];
  const float* ar   = (const float*)d_in[3];
  const float* bias = (const float*)d_in[4];
  const int*   src  = (const int*)d_in[5];
  const int*   dst  = (const int*)d_in[6];
  float* out = (float*)d_out;

  // workspace layout (bytes), total ~232 MB
  char* p = (char*)d_ws;
  unsigned short* xb   = (unsigned short*)p; p += (size_t)RN * RIN * 2;        // 51.2 MB
  unsigned short* wbt  = (unsigned short*)p; p += (size_t)RR * RIN * RHF * 2;  // 0.39 MB
  unsigned short* zb   = (unsigned short*)p; p += (size_t)RR * RN * RHF * 2;   // 153.6 MB
  unsigned short* elh  = (unsigned short*)p; p += (size_t)N3 * RH * 2;         // 2.4 MB
  unsigned short* erh  = (unsigned short*)p; p += (size_t)N3 * RH * 2;         // 2.4 MB
  int* deg2    = (int*)p;    p += (size_t)N3 * 4;                              // 1.2 MB
  int* offs2   = (int*)p;    p += (size_t)N3 * 4;                              // 1.2 MB
  int* czoff   = (int*)p;    p += (size_t)NE3 * 4;                             // 6.0 MB
  unsigned short* ceeh = (unsigned short*)p; p += (size_t)NE3 * RH * 2;        // 12.0 MB
  int* bsum    = (int*)p;    p += 2048;

  const int NB1 = (N3 + 1023) / 1024;   // 293

  hipMemsetAsync(deg2, 0, (size_t)N3 * 4, stream);

  rgat_prep<<<CVX_BLOCKS + CVW_BLOCKS + HIST_BLOCKS, 256, 0, stream>>>(
      x, xb, W, wbt, dst, deg2);

  rgat_scan1<<<NB1, 256, 0, stream>>>(deg2, offs2, bsum);
  rgat_scan2<<<1, 512, 0, stream>>>(bsum, NB1);
  rgat_scan3<<<NB1, 256, 0, stream>>>(offs2, bsum);

  rgat_gemm_bf16<<<dim3((RN + 127) / 128, RR), 256, 0, stream>>>(
      xb, wbt, zb, al, ar, elh, erh);

  rgat_scatter<<<(NE3 + 255) / 256, 256, 0, stream>>>(src, dst, elh, erh, offs2,
                                                      czoff, ceeh);

  rgat_norm<<<(N3 + 255) / 256, 256, 0, stream>>>(ceeh, deg2, offs2);

  rgat_aggregate<<<RN, 256, 0, stream>>>(zb, czoff, ceeh, deg2, offs2, bias, out);
}